// Round 8
// baseline (95.730 us; speedup 1.0000x reference)
//
#include <hip/hip_runtime.h>

typedef unsigned long long u64;
typedef unsigned int u32;

#define HH 512
#define WW 512
#define BATCH 32
#define NPIX (BATCH*HH*WW)
#define WPI (HH*WW/64)      /* u64 words per image = 4096 */
#define WPR (WW/64)         /* u64 words per row = 8 */

#define STRIPS 16
#define PS_BLOCKS (BATCH*STRIPS)   /* 512 */

#define MAIN_BLOCKS 2048
#define MAIN_THREADS 256

#define SEARCH_BLOCKS 512
#define WINMASK ((((1ULL<<49)-1)) << 8)   /* dx in [-24,24] of the 64-bit window */

/* workspace layout (bytes) */
#define WS_CTR    0          /* u32[2]: qcnt, main-done counter (memset 8B each call) */
#define WS_MAINP  4096       /* double mainP[6][MAIN_BLOCKS] = 96 KiB */
#define WS_SRCHP  102400     /* double searchP[SEARCH_BLOCKS] = 4 KiB */
#define WS_TBITS  131072     /* u64[NPIX/64] = 1 MiB */
#define WS_BMBITS 1179648    /* u64[NPIX/64] = 1 MiB */
#define WS_QBUF   2228224    /* u32[NPIX] worst case = 32 MiB */

__device__ __forceinline__ float hw_exp2(float x) { return __builtin_amdgcn_exp2f(x); }
__device__ __forceinline__ float hw_log2(float x) { return __builtin_amdgcn_logf(x); }

// ============ fused pack + stencil + searcher-queue build ============
// Each block: one 32-row strip of one image. LDS holds 36 rows (2-row halo) of
// bit-packed targets. Phase 1 packs floats->bits, phase 2 computes
// edge=t&~erode3x3(t), bmask=dilate3x3(edge), writes tbits/bmbits words, and
// appends all bmask==0 pixels to the global searcher queue (block-compacted).
__global__ __launch_bounds__(256) void pack_stencil_kernel(
        const float4* __restrict__ t4, u64* __restrict__ tbits,
        u64* __restrict__ bmbits, u32* __restrict__ qcnt, u32* __restrict__ qbuf) {
    __shared__ u64 lw[36][9];          /* 72B row stride (9th word = pad) */
    __shared__ int blkcnt;
    __shared__ u32 gbase;

    const int blk = blockIdx.x;
    const int img = blk >> 4;
    const int strip = blk & 15;
    const int row0 = strip * 32;
    if (threadIdx.x == 0) blkcnt = 0;

    unsigned char* lb = (unsigned char*)lw;
    #pragma unroll
    for (int it = 0; it < 9; ++it) {
        int i = it * 256 + threadIdx.x;    /* 0..2303: 36 rows x 64 bytes */
        int r = i >> 6, c = i & 63;
        int gy = row0 - 2 + r;
        unsigned b = 0;
        if (gy >= 0 && gy < HH) {
            int base = img * (HH*WW/4) + gy * (WW/4) + c * 2;
            float4 lo = t4[base], hi = t4[base + 1];
            b =  (lo.x > 0.5f)       | ((lo.y > 0.5f) << 1)
              | ((lo.z > 0.5f) << 2) | ((lo.w > 0.5f) << 3)
              | ((hi.x > 0.5f) << 4) | ((hi.y > 0.5f) << 5)
              | ((hi.z > 0.5f) << 6) | ((hi.w > 0.5f) << 7);
        }
        lb[r * 72 + c] = (unsigned char)b;
    }
    __syncthreads();

    const int r  = threadIdx.x >> 3;   /* 0..31 owned row   */
    const int wc = threadIdx.x & 7;    /* 0..7 word col     */

    u64 w[5][5];
    #pragma unroll
    for (int dr = 0; dr < 5; ++dr)
        #pragma unroll
        for (int dc = 0; dc < 5; ++dc) {
            int cc = wc + dc - 2;
            w[dr][dc] = (cc >= 0 && cc < 8) ? lw[r + dr][cc] : 0ULL;
        }

    u64 ha[5][3];
    #pragma unroll
    for (int rr = 0; rr < 5; ++rr)
        #pragma unroll
        for (int j = 0; j < 3; ++j) {
            u64 C = w[rr][j + 1], L = w[rr][j], R = w[rr][j + 2];
            ha[rr][j] = ((C << 1) | (L >> 63)) & C & ((C >> 1) | (R << 63));
        }

    u64 eg[3][3];
    #pragma unroll
    for (int i = 0; i < 3; ++i)
        #pragma unroll
        for (int j = 0; j < 3; ++j) {
            u64 er = ha[i][j] & ha[i + 1][j] & ha[i + 2][j];
            eg[i][j] = w[i + 1][j + 1] & ~er;
        }

    u64 out = 0ULL;
    #pragma unroll
    for (int i = 0; i < 3; ++i) {
        u64 E = eg[i][1], L = eg[i][0], R = eg[i][2];
        out |= ((E << 1) | (L >> 63)) | E | ((E >> 1) | (R << 63));
    }

    int gw = img * WPI + (row0 + r) * WPR + wc;
    tbits[gw]  = w[2][2];
    bmbits[gw] = out;

    /* enqueue searcher pixels (bmask==0) */
    u64 m = ~out;
    int nz = __popcll(m);
    int lbase = atomicAdd(&blkcnt, nz);
    __syncthreads();
    if (threadIdx.x == 0) gbase = atomicAdd(qcnt, (u32)blkcnt);
    __syncthreads();
    u32 o = gbase + (u32)lbase;
    int pixbase = img * (HH * WW) + (row0 + r) * WW + wc * 64;
    while (m) {
        int b = __builtin_ctzll(m);
        qbuf[o++] = (u32)(pixbase + b);
        m &= m - 1;
    }
}

// nearest set-bit horizontal distance within +/-24 of x0 on one bit-packed row; 99 if none
__device__ __forceinline__ int rowscan(const u64* __restrict__ row, int x0) {
    int s = x0 - 32;
    int wi = s >> 6;
    int sh = s & 63;
    u64 lo = (wi >= 0 && wi < WPR) ? row[wi] : 0ULL;
    u64 hi = ((wi + 1) < WPR) ? row[wi + 1] : 0ULL;
    u64 win = sh ? ((lo >> sh) | (hi << (64 - sh))) : lo;
    win &= WINMASK;
    u64 left = win << 32;
    u64 right = win >> 32;
    int dl = left ? (__builtin_clzll(left) + 1) : 99;
    int dr = right ? __builtin_ctzll(right) : 99;
    return dl < dr ? dl : dr;
}

// full chamfer weight for one non-boundary pixel
__device__ __forceinline__ float search_weight(const u64* __restrict__ img, int pix) {
    const float L2E = 1.44269504f;
    int x0 = pix & (WW - 1);
    int y0 = (pix >> 9) & (HH - 1);
    float best = 1e9f;
    for (int ady = 0; ady <= 24; ++ady) {
        if ((float)ady >= best) break;
        int hd = 99;
        int yU = y0 - ady;
        if (yU >= 0) hd = rowscan(img + yU * WPR, x0);
        int yD = y0 + ady;
        if (ady > 0 && yD < HH) {
            int h2 = rowscan(img + yD * WPR, x0);
            hd = h2 < hd ? h2 : hd;
        }
        if (hd <= 24) {
            float h = (float)hd, ay = (float)ady;
            float mx = fmaxf(h, ay), mn = fminf(h, ay);
            best = fminf(best, mx + 0.4142135f * mn);
        }
    }
    return (best < 1e8f) ? (hw_exp2(best * (-L2E / 3.0f)) + 0.1f) : 0.1f;
}

// ============ dense searcher kernel: sum bnd(pix)*w(pix) over the queue ============
__global__ __launch_bounds__(256) void search_kernel(
        const float* __restrict__ x, const u64* __restrict__ tbits,
        const u64* __restrict__ bmbits, const u32* __restrict__ qcnt,
        const u32* __restrict__ qbuf, double* __restrict__ searchP) {
    const float L2E = 1.44269504f, LN2 = 0.69314718f, LOGCLIP = 16.11809565f;
    int n = (int)*qcnt;
    float acc = 0.f;
    for (int i = blockIdx.x * 256 + threadIdx.x; i < n; i += SEARCH_BLOCKS * 256) {
        int pix = (int)qbuf[i];
        float xv = x[pix];
        int tb = (int)((tbits[pix >> 6] >> (pix & 63)) & 1ULL);
        float ax = fabsf(xv);
        float e = hw_exp2(ax * -L2E);
        float l1pe = hw_log2(1.0f + e) * LN2;
        float sp_neg = fmaxf(-xv, 0.0f) + l1pe;
        float sp = tb ? sp_neg : (sp_neg + xv);
        float bnd = fminf(sp, LOGCLIP);
        float wgt = search_weight(bmbits + (pix >> 18) * WPI, pix);
        acc += bnd * wgt;
    }
    double d = acc;
    #pragma unroll
    for (int off = 32; off > 0; off >>= 1) d += __shfl_down(d, off);
    __shared__ double red[4];
    int lane = threadIdx.x & 63, wid = threadIdx.x >> 6;
    if (lane == 0) red[wid] = d;
    __syncthreads();
    if (threadIdx.x == 0)
        searchP[blockIdx.x] = red[0] + red[1] + red[2] + red[3];
}

// ============ branchless streaming reductions + last-block finalize ============
__global__ __launch_bounds__(256) void main_kernel(
        const float4* __restrict__ x4, const u64* __restrict__ tbits,
        const u64* __restrict__ bmbits,
        const float* __restrict__ alpha_p, const float* __restrict__ gamma_p,
        double* __restrict__ mainP, const double* __restrict__ searchP,
        u32* __restrict__ cnt, float* __restrict__ out) {
    __shared__ double red[4][6];
    __shared__ int amLast;

    const float a = fminf(fmaxf(alpha_p[0], 0.1f), 0.9f);
    const float one_m_a = 1.0f - a;
    const float g = fminf(fmaxf(gamma_p[0], 1.0f), 5.0f);
    const float gr = rintf(g);
    const bool gint = (g == gr);
    const int gi = (int)gr;
    const float LOGCLIP = 16.11809565f;
    const float L2E = 1.44269504f;
    const float LN2 = 0.69314718f;

    float s_p = 0.f, s_pt = 0.f, s_f = 0.f, s_b = 0.f, s_bnd = 0.f;
    int c_t = 0;

    const int base = blockIdx.x * 1024 + threadIdx.x;   /* float4 index */
    float4 xv[4];
    u32 tn[4], bn[4];
    #pragma unroll
    for (int j = 0; j < 4; ++j) {
        int q = base + j * 256;
        xv[j] = x4[q];
        int sh = (q & 15) * 4;
        tn[j] = (u32)((tbits[q >> 4]  >> sh) & 0xfULL);
        bn[j] = (u32)((bmbits[q >> 4] >> sh) & 0xfULL);
    }

    #pragma unroll
    for (int j = 0; j < 4; ++j) {
        float xs[4] = {xv[j].x, xv[j].y, xv[j].z, xv[j].w};
        #pragma unroll
        for (int k = 0; k < 4; ++k) {
            float xvv = xs[k];
            int tb = (int)((tn[j] >> k) & 1u);
            int bm = (int)((bn[j] >> k) & 1u);

            float ax = fabsf(xvv);
            float e  = hw_exp2(ax * -L2E);
            float rc = __builtin_amdgcn_rcpf(1.0f + e);
            float p  = (xvv >= 0.0f) ? rc : e * rc;
            float l1pe = hw_log2(1.0f + e) * LN2;
            float sp_neg = fmaxf(-xvv, 0.0f) + l1pe;
            float sp_pos = sp_neg + xvv;

            float bce_el = sp_neg + (tb ? 0.025f : 0.975f) * xvv;
            float q95 = 0.95f * p;
            float u   = tb ? (0.975f - q95) : (0.025f + q95);
            float a_t = tb ? a : one_m_a;
            float pw;
            if (gint) {
                float u2 = u * u;
                pw = (gi == 1) ? u : (gi == 2) ? u2 : (gi == 3) ? u2 * u
                   : (gi == 4) ? u2 * u2 : u2 * u2 * u;
            } else {
                pw = hw_exp2(g * hw_log2(u));
            }
            float focal_el = a_t * pw * bce_el;

            float bce2 = tb ? 7.0f * sp_neg : sp_pos;
            float bnd  = fminf(tb ? sp_neg : sp_pos, LOGCLIP);

            s_p   += p;
            c_t   += tb;
            s_pt  += tb ? p : 0.0f;
            s_f   += focal_el;
            s_b   += bce2;
            s_bnd += bm ? bnd : 0.0f;    /* searchers handled by search_kernel */
        }
    }

    double d_p = s_p, d_t = (double)c_t, d_pt = s_pt, d_f = s_f, d_b = s_b;
    double d_bnd = (double)s_bnd * 1.1;

    #pragma unroll
    for (int off = 32; off > 0; off >>= 1) {
        d_p   += __shfl_down(d_p, off);
        d_t   += __shfl_down(d_t, off);
        d_pt  += __shfl_down(d_pt, off);
        d_f   += __shfl_down(d_f, off);
        d_b   += __shfl_down(d_b, off);
        d_bnd += __shfl_down(d_bnd, off);
    }

    int lane = threadIdx.x & 63, wid = threadIdx.x >> 6;
    if (lane == 0) {
        red[wid][0] = d_p;  red[wid][1] = d_t;  red[wid][2] = d_pt;
        red[wid][3] = d_f;  red[wid][4] = d_b;  red[wid][5] = d_bnd;
    }
    __syncthreads();
    if (threadIdx.x == 0) {
        #pragma unroll
        for (int i = 0; i < 6; ++i)
            mainP[i * MAIN_BLOCKS + blockIdx.x] =
                red[0][i] + red[1][i] + red[2][i] + red[3][i];
        __threadfence();
        u32 old = atomicAdd(cnt, 1u);
        amLast = (old == MAIN_BLOCKS - 1);
    }
    __syncthreads();

    if (amLast) {
        __threadfence();
        double s[6] = {0, 0, 0, 0, 0, 0};
        for (int b = threadIdx.x; b < MAIN_BLOCKS; b += 256)
            #pragma unroll
            for (int i = 0; i < 6; ++i) s[i] += mainP[i * MAIN_BLOCKS + b];
        for (int b = threadIdx.x; b < SEARCH_BLOCKS; b += 256)
            s[5] += searchP[b];

        #pragma unroll
        for (int off = 32; off > 0; off >>= 1)
            #pragma unroll
            for (int i = 0; i < 6; ++i) s[i] += __shfl_down(s[i], off);

        __syncthreads();   /* red[] reuse: earlier reads done */
        if (lane == 0)
            #pragma unroll
            for (int i = 0; i < 6; ++i) red[wid][i] = s[i];
        __syncthreads();

        if (threadIdx.x == 0) {
            double S_p = red[0][0] + red[1][0] + red[2][0] + red[3][0];
            double S_t = red[0][1] + red[1][1] + red[2][1] + red[3][1];
            double S_pt = red[0][2] + red[1][2] + red[2][2] + red[3][2];
            double S_f = red[0][3] + red[1][3] + red[2][3] + red[3][3];
            double S_b = red[0][4] + red[1][4] + red[2][4] + red[3][4];
            double S_bnd = red[0][5] + red[1][5] + red[2][5] + red[3][5];
            const double N = (double)NPIX;
            double inter = S_pt;
            double card = S_p + S_t;
            double dice_score = (2.0 * inter + 1e-6) / fmax(card + 1e-6, 1e-7);
            double dice = (S_t > 0.0) ? (1.0 - dice_score) : 0.0;
            double focal = S_f / N;
            double bce = S_b / N;
            double pos_ratio = S_t / N;
            double da = 0.7 * (1.0 + pos_ratio);
            double db = 0.3 * (2.0 - pos_ratio);
            double fn = S_t - S_pt;
            double fp = (S_p - S_pt) * 3.0;
            double tversky = 1.0 - (S_pt + 1e-6) / (S_pt + da * fn + db * fp + 1e-6);
            double bnd = S_bnd / N;
            out[0] = (float)(0.35 * dice + 0.25 * focal + 0.15 * bce + 0.15 * tversky + 0.1 * bnd);
        }
    }
}

extern "C" void kernel_launch(void* const* d_in, const int* in_sizes, int n_in,
                              void* d_out, int out_size, void* d_ws, size_t ws_size,
                              hipStream_t stream) {
    const float* inputs  = (const float*)d_in[0];
    const float* targets = (const float*)d_in[1];
    const float* alpha_p = (const float*)d_in[2];
    const float* gamma_p = (const float*)d_in[3];
    float* out = (float*)d_out;

    char* ws = (char*)d_ws;
    u32*    ctrs    = (u32*)(ws + WS_CTR);       /* [0]=qcnt [1]=main done */
    double* mainP   = (double*)(ws + WS_MAINP);
    double* searchP = (double*)(ws + WS_SRCHP);
    u64*    tbits   = (u64*)(ws + WS_TBITS);
    u64*    bmbits  = (u64*)(ws + WS_BMBITS);
    u32*    qbuf    = (u32*)(ws + WS_QBUF);

    hipMemsetAsync(ctrs, 0, 8, stream);

    pack_stencil_kernel<<<PS_BLOCKS, 256, 0, stream>>>(
        (const float4*)targets, tbits, bmbits, &ctrs[0], qbuf);

    search_kernel<<<SEARCH_BLOCKS, 256, 0, stream>>>(
        inputs, tbits, bmbits, &ctrs[0], qbuf, searchP);

    main_kernel<<<MAIN_BLOCKS, 256, 0, stream>>>(
        (const float4*)inputs, tbits, bmbits, alpha_p, gamma_p,
        mainP, searchP, &ctrs[1], out);
}

// Round 9
// 55.605 us; speedup vs baseline: 1.7216x; 1.7216x over previous
//
#include <hip/hip_runtime.h>

typedef unsigned long long u64;
typedef unsigned int u32;

#define HH 512
#define WW 512
#define BATCH 32
#define NPIX (BATCH*HH*WW)
#define NWORDS (NPIX/64)
#define WPI (HH*WW/64)      /* u64 words per image = 4096 */
#define WPR (WW/64)         /* u64 words per row = 8 */

#define PS_BLOCKS (BATCH*16)       /* 512: one 32-row strip each */
#define MAIN_BLOCKS 4096
#define MAIN_THREADS 256
#define MAIN_IT 2                  /* 8 px/thread */
#define SEARCH_BLOCKS (NWORDS/256) /* 512 */
#define WINMASK ((((1ULL<<49)-1)) << 8)   /* dx in [-24,24] of the 64-bit window */

/* workspace layout (bytes) */
#define WS_MAINP  0          /* double mainP[MAIN_BLOCKS*6] = 192 KiB */
#define WS_SRCHP  196608     /* double searchP[SEARCH_BLOCKS] = 4 KiB */
#define WS_TBITS  262144     /* u64[NWORDS] = 1 MiB */
#define WS_BMBITS 1310720    /* u64[NWORDS] = 1 MiB */

__device__ __forceinline__ float hw_exp2(float x) { return __builtin_amdgcn_exp2f(x); }
__device__ __forceinline__ float hw_log2(float x) { return __builtin_amdgcn_logf(x); }

// ============ fused pack + stencil (no queue build) ============
__global__ __launch_bounds__(256) void pack_stencil_kernel(
        const float4* __restrict__ t4, u64* __restrict__ tbits,
        u64* __restrict__ bmbits) {
    __shared__ u64 lw[36][9];          /* 72B row stride (9th word = pad) */

    const int blk = blockIdx.x;
    const int img = blk >> 4;
    const int strip = blk & 15;
    const int row0 = strip * 32;

    unsigned char* lb = (unsigned char*)lw;
    #pragma unroll
    for (int it = 0; it < 9; ++it) {
        int i = it * 256 + threadIdx.x;    /* 0..2303: 36 rows x 64 bytes */
        int r = i >> 6, c = i & 63;
        int gy = row0 - 2 + r;
        unsigned b = 0;
        if (gy >= 0 && gy < HH) {
            int base = img * (HH*WW/4) + gy * (WW/4) + c * 2;
            float4 lo = t4[base], hi = t4[base + 1];
            b =  (lo.x > 0.5f)       | ((lo.y > 0.5f) << 1)
              | ((lo.z > 0.5f) << 2) | ((lo.w > 0.5f) << 3)
              | ((hi.x > 0.5f) << 4) | ((hi.y > 0.5f) << 5)
              | ((hi.z > 0.5f) << 6) | ((hi.w > 0.5f) << 7);
        }
        lb[r * 72 + c] = (unsigned char)b;
    }
    __syncthreads();

    const int r  = threadIdx.x >> 3;   /* 0..31 owned row */
    const int wc = threadIdx.x & 7;    /* 0..7 word col   */

    u64 w[5][5];
    #pragma unroll
    for (int dr = 0; dr < 5; ++dr)
        #pragma unroll
        for (int dc = 0; dc < 5; ++dc) {
            int cc = wc + dc - 2;
            w[dr][dc] = (cc >= 0 && cc < 8) ? lw[r + dr][cc] : 0ULL;
        }

    u64 ha[5][3];
    #pragma unroll
    for (int rr = 0; rr < 5; ++rr)
        #pragma unroll
        for (int j = 0; j < 3; ++j) {
            u64 C = w[rr][j + 1], L = w[rr][j], R = w[rr][j + 2];
            ha[rr][j] = ((C << 1) | (L >> 63)) & C & ((C >> 1) | (R << 63));
        }

    u64 eg[3][3];
    #pragma unroll
    for (int i = 0; i < 3; ++i)
        #pragma unroll
        for (int j = 0; j < 3; ++j) {
            u64 er = ha[i][j] & ha[i + 1][j] & ha[i + 2][j];
            eg[i][j] = w[i + 1][j + 1] & ~er;
        }

    u64 out = 0ULL;
    #pragma unroll
    for (int i = 0; i < 3; ++i) {
        u64 E = eg[i][1], L = eg[i][0], R = eg[i][2];
        out |= ((E << 1) | (L >> 63)) | E | ((E >> 1) | (R << 63));
    }

    int gw = img * WPI + (row0 + r) * WPR + wc;
    tbits[gw]  = w[2][2];
    bmbits[gw] = out;
}

// nearest set-bit horizontal distance within +/-24 of x0 on one bit-packed row; 99 if none
__device__ __forceinline__ int rowscan(const u64* __restrict__ row, int x0) {
    int s = x0 - 32;
    int wi = s >> 6;
    int sh = s & 63;
    u64 lo = (wi >= 0 && wi < WPR) ? row[wi] : 0ULL;
    u64 hi = ((wi + 1) < WPR) ? row[wi + 1] : 0ULL;
    u64 win = sh ? ((lo >> sh) | (hi << (64 - sh))) : lo;
    win &= WINMASK;
    u64 left = win << 32;
    u64 right = win >> 32;
    int dl = left ? (__builtin_clzll(left) + 1) : 99;
    int dr = right ? __builtin_ctzll(right) : 99;
    return dl < dr ? dl : dr;
}

// full chamfer weight for one non-boundary pixel (pix may include image offset; masked)
__device__ __forceinline__ float search_weight(const u64* __restrict__ img, int pix) {
    const float L2E = 1.44269504f;
    int x0 = pix & (WW - 1);
    int y0 = (pix >> 9) & (HH - 1);
    float best = 1e9f;
    for (int ady = 0; ady <= 24; ++ady) {
        if ((float)ady >= best) break;
        int hd = 99;
        int yU = y0 - ady;
        if (yU >= 0) hd = rowscan(img + yU * WPR, x0);
        int yD = y0 + ady;
        if (ady > 0 && yD < HH) {
            int h2 = rowscan(img + yD * WPR, x0);
            hd = h2 < hd ? h2 : hd;
        }
        if (hd <= 24) {
            float h = (float)hd, ay = (float)ady;
            float mx = fmaxf(h, ay), mn = fminf(h, ay);
            best = fminf(best, mx + 0.4142135f * mn);
        }
    }
    return (best < 1e8f) ? (hw_exp2(best * (-L2E / 3.0f)) + 0.1f) : 0.1f;
}

// ============ search: one thread per u64 word, handle its zero bits ============
__global__ __launch_bounds__(256) void search_kernel(
        const float* __restrict__ x, const u64* __restrict__ tbits,
        const u64* __restrict__ bmbits, double* __restrict__ searchP) {
    const float L2E = 1.44269504f, LN2 = 0.69314718f, LOGCLIP = 16.11809565f;
    int wi = blockIdx.x * 256 + threadIdx.x;
    u64 bw = bmbits[wi];
    u64 tw = tbits[wi];
    u64 m = ~bw;
    const u64* img = bmbits + (wi >> 12) * WPI;
    int pixbase = wi * 64;
    float acc = 0.f;
    while (m) {
        int b = __builtin_ctzll(m);
        m &= m - 1;
        int pix = pixbase + b;
        float xv = x[pix];
        int tb = (int)((tw >> b) & 1ULL);
        float ax = fabsf(xv);
        float e = hw_exp2(ax * -L2E);
        float l1pe = hw_log2(1.0f + e) * LN2;
        float sp_neg = fmaxf(-xv, 0.0f) + l1pe;
        float sp = tb ? sp_neg : (sp_neg + xv);
        float bnd = fminf(sp, LOGCLIP);
        acc += bnd * search_weight(img, pix);
    }
    double d = acc;
    #pragma unroll
    for (int off = 32; off > 0; off >>= 1) d += __shfl_down(d, off);
    __shared__ double red[4];
    int lane = threadIdx.x & 63, wid = threadIdx.x >> 6;
    if (lane == 0) red[wid] = d;
    __syncthreads();
    if (threadIdx.x == 0)
        searchP[blockIdx.x] = red[0] + red[1] + red[2] + red[3];
}

// ============ branchless streaming reductions (proven r6/7 loop shape) ============
__global__ __launch_bounds__(MAIN_THREADS, 6) void main_kernel(
        const float4* __restrict__ x4, const u64* __restrict__ tbits,
        const u64* __restrict__ bmbits,
        const float* __restrict__ alpha_p, const float* __restrict__ gamma_p,
        double* __restrict__ mainP) {
    __shared__ double red[4][6];

    const float a = fminf(fmaxf(alpha_p[0], 0.1f), 0.9f);
    const float one_m_a = 1.0f - a;
    const float g = fminf(fmaxf(gamma_p[0], 1.0f), 5.0f);
    const float gr = rintf(g);
    const bool gint = (g == gr);
    const int gi = (int)gr;
    const float LOGCLIP = 16.11809565f;
    const float L2E = 1.44269504f;
    const float LN2 = 0.69314718f;

    float s_p = 0.f, s_pt = 0.f, s_f = 0.f, s_b = 0.f, s_bnd = 0.f;
    int c_t = 0;

    #pragma unroll 1
    for (int it = 0; it < MAIN_IT; ++it) {
        int q = (it * MAIN_BLOCKS + blockIdx.x) * MAIN_THREADS + threadIdx.x;
        float4 xv4 = x4[q];
        int pix0 = q * 4;
        int sh = pix0 & 63;
        u64 tw = tbits[pix0 >> 6] >> sh;
        u64 bw = bmbits[pix0 >> 6] >> sh;
        float xs[4] = {xv4.x, xv4.y, xv4.z, xv4.w};

        #pragma unroll
        for (int k = 0; k < 4; ++k) {
            float xv = xs[k];
            int tb = (int)((tw >> k) & 1ULL);
            int bm = (int)((bw >> k) & 1ULL);

            float ax = fabsf(xv);
            float e  = hw_exp2(ax * -L2E);             // exp(-|x|)
            float rc = __builtin_amdgcn_rcpf(1.0f + e);
            float p  = (xv >= 0.0f) ? rc : e * rc;     // sigmoid
            float l1pe = hw_log2(1.0f + e) * LN2;      // log(1+exp(-|x|))
            float sp_neg = fmaxf(-xv, 0.0f) + l1pe;    // softplus(-x)
            float sp_pos = sp_neg + xv;                // softplus(x)

            float bce_el = sp_neg + (tb ? 0.025f : 0.975f) * xv;
            float q95 = 0.95f * p;
            float u   = tb ? (0.975f - q95) : (0.025f + q95);   // 1 - p_t
            float a_t = tb ? a : one_m_a;
            float pw;
            if (gint) {
                float u2 = u * u;
                pw = (gi == 1) ? u : (gi == 2) ? u2 : (gi == 3) ? u2 * u
                   : (gi == 4) ? u2 * u2 : u2 * u2 * u;
            } else {
                pw = hw_exp2(g * hw_log2(u));
            }
            float focal_el = a_t * pw * bce_el;

            float bce2 = tb ? 7.0f * sp_neg : sp_pos;
            float bnd  = fminf(tb ? sp_neg : sp_pos, LOGCLIP);

            s_p   += p;
            c_t   += tb;
            s_pt  += tb ? p : 0.0f;
            s_f   += focal_el;
            s_b   += bce2;
            s_bnd += bm ? bnd : 0.0f;    /* searchers handled by search_kernel */
        }
    }

    double d_p = s_p, d_t = (double)c_t, d_pt = s_pt, d_f = s_f, d_b = s_b;
    double d_bnd = (double)s_bnd * 1.1;

    #pragma unroll
    for (int off = 32; off > 0; off >>= 1) {
        d_p   += __shfl_down(d_p, off);
        d_t   += __shfl_down(d_t, off);
        d_pt  += __shfl_down(d_pt, off);
        d_f   += __shfl_down(d_f, off);
        d_b   += __shfl_down(d_b, off);
        d_bnd += __shfl_down(d_bnd, off);
    }

    int lane = threadIdx.x & 63, wid = threadIdx.x >> 6;
    if (lane == 0) {
        red[wid][0] = d_p;  red[wid][1] = d_t;  red[wid][2] = d_pt;
        red[wid][3] = d_f;  red[wid][4] = d_b;  red[wid][5] = d_bnd;
    }
    __syncthreads();
    if (threadIdx.x == 0) {
        #pragma unroll
        for (int i = 0; i < 6; ++i)
            mainP[blockIdx.x * 6 + i] = red[0][i] + red[1][i] + red[2][i] + red[3][i];
    }
}

// ============ final reduction + loss assembly ============
__global__ __launch_bounds__(256) void reduce_kernel(const double* __restrict__ mainP,
                                                     const double* __restrict__ searchP,
                                                     float* __restrict__ out) {
    double s[6] = {0, 0, 0, 0, 0, 0};
    for (int b = threadIdx.x; b < MAIN_BLOCKS; b += 256)
        #pragma unroll
        for (int i = 0; i < 6; ++i) s[i] += mainP[b * 6 + i];
    for (int b = threadIdx.x; b < SEARCH_BLOCKS; b += 256)
        s[5] += searchP[b];

    #pragma unroll
    for (int off = 32; off > 0; off >>= 1)
        #pragma unroll
        for (int i = 0; i < 6; ++i) s[i] += __shfl_down(s[i], off);

    __shared__ double red[4][6];
    int lane = threadIdx.x & 63, wid = threadIdx.x >> 6;
    if (lane == 0)
        #pragma unroll
        for (int i = 0; i < 6; ++i) red[wid][i] = s[i];
    __syncthreads();

    if (threadIdx.x == 0) {
        double S_p = red[0][0] + red[1][0] + red[2][0] + red[3][0];
        double S_t = red[0][1] + red[1][1] + red[2][1] + red[3][1];
        double S_pt = red[0][2] + red[1][2] + red[2][2] + red[3][2];
        double S_f = red[0][3] + red[1][3] + red[2][3] + red[3][3];
        double S_b = red[0][4] + red[1][4] + red[2][4] + red[3][4];
        double S_bnd = red[0][5] + red[1][5] + red[2][5] + red[3][5];
        const double N = (double)NPIX;
        double inter = S_pt;
        double card = S_p + S_t;
        double dice_score = (2.0 * inter + 1e-6) / fmax(card + 1e-6, 1e-7);
        double dice = (S_t > 0.0) ? (1.0 - dice_score) : 0.0;
        double focal = S_f / N;
        double bce = S_b / N;
        double pos_ratio = S_t / N;
        double da = 0.7 * (1.0 + pos_ratio);
        double db = 0.3 * (2.0 - pos_ratio);
        double fn = S_t - S_pt;
        double fp = (S_p - S_pt) * 3.0;
        double tversky = 1.0 - (S_pt + 1e-6) / (S_pt + da * fn + db * fp + 1e-6);
        double bnd = S_bnd / N;
        out[0] = (float)(0.35 * dice + 0.25 * focal + 0.15 * bce + 0.15 * tversky + 0.1 * bnd);
    }
}

extern "C" void kernel_launch(void* const* d_in, const int* in_sizes, int n_in,
                              void* d_out, int out_size, void* d_ws, size_t ws_size,
                              hipStream_t stream) {
    const float* inputs  = (const float*)d_in[0];
    const float* targets = (const float*)d_in[1];
    const float* alpha_p = (const float*)d_in[2];
    const float* gamma_p = (const float*)d_in[3];
    float* out = (float*)d_out;

    char* ws = (char*)d_ws;
    double* mainP   = (double*)(ws + WS_MAINP);
    double* searchP = (double*)(ws + WS_SRCHP);
    u64*    tbits   = (u64*)(ws + WS_TBITS);
    u64*    bmbits  = (u64*)(ws + WS_BMBITS);

    pack_stencil_kernel<<<PS_BLOCKS, 256, 0, stream>>>(
        (const float4*)targets, tbits, bmbits);

    search_kernel<<<SEARCH_BLOCKS, 256, 0, stream>>>(
        inputs, tbits, bmbits, searchP);

    main_kernel<<<MAIN_BLOCKS, MAIN_THREADS, 0, stream>>>(
        (const float4*)inputs, tbits, bmbits, alpha_p, gamma_p, mainP);

    reduce_kernel<<<1, 256, 0, stream>>>(mainP, searchP, out);
}